// Round 1
// baseline (40.903 us; speedup 1.0000x reference)
//
#include <hip/hip_runtime.h>

// DiscreteLinear: z[b,i] = sum_j weight[a[b],i,j] * x[b,j] + bias[a[b],i]
// B=2048, A=64, D=512. Strategy: bucket samples by action, then one grouped
// GEMM where each expert's 1MB weight matrix is streamed exactly once.

#define NA 64
#define DD 512
#define NB 2048

typedef __bf16  bf16x8  __attribute__((ext_vector_type(8)));
typedef float   floatx4 __attribute__((ext_vector_type(4)));

static __device__ inline bf16x8 cvt8(floatx4 lo, floatx4 hi) {
    bf16x8 r;
    r[0] = (__bf16)lo[0]; r[1] = (__bf16)lo[1];
    r[2] = (__bf16)lo[2]; r[3] = (__bf16)lo[3];
    r[4] = (__bf16)hi[0]; r[5] = (__bf16)hi[1];
    r[6] = (__bf16)hi[2]; r[7] = (__bf16)hi[3];
    return r;
}

// Single block: histogram actions, exclusive scan, scatter sample indices.
__global__ void dl_bucket(const int* __restrict__ act,
                          int* __restrict__ counts,
                          int* __restrict__ offsets,
                          int* __restrict__ perm) {
    __shared__ int s_cnt[NA];
    __shared__ int s_off[NA];
    const int t = threadIdx.x;
    if (t < NA) s_cnt[t] = 0;
    __syncthreads();
    for (int b = t; b < NB; b += 256) atomicAdd(&s_cnt[act[b]], 1);
    __syncthreads();
    if (t == 0) {
        int run = 0;
        for (int i = 0; i < NA; ++i) { s_off[i] = run; run += s_cnt[i]; }
    }
    __syncthreads();
    if (t < NA) { counts[t] = s_cnt[t]; offsets[t] = s_off[t]; }
    __syncthreads();
    for (int b = t; b < NB; b += 256) {
        int pos = atomicAdd(&s_off[act[b]], 1);   // s_off now acts as cursor
        perm[pos] = b;
    }
}

// Grouped GEMM: grid = (8 n-tiles, 64 actions), block = 256 threads (4 waves).
// Each wave owns 16 output columns; block covers 64 columns x up to 64 rows
// per m-supertile. Accumulators for 4 m-chunks are kept live across the K
// loop so each W element is loaded exactly once per block.
__global__ __launch_bounds__(256) void dl_gemm(
        const float* __restrict__ x,
        const float* __restrict__ weight,
        const float* __restrict__ bias,
        const int*   __restrict__ counts,
        const int*   __restrict__ offsets,
        const int*   __restrict__ perm,
        float*       __restrict__ out)
{
    const int a   = blockIdx.y;
    const int cnt = counts[a];
    if (cnt == 0) return;
    const int base = offsets[a];

    const int tid  = threadIdx.x;
    const int wave = tid >> 6;
    const int lane = tid & 63;
    const int l16  = lane & 15;
    const int kgrp = lane >> 4;                       // 0..3, k-subgroup of 8
    const int ncol = blockIdx.x * 64 + wave * 16 + l16;

    // This lane's W row (column n of the logical B operand), k-sliced.
    const float* wrow   = weight + ((size_t)a * DD + ncol) * DD + kgrp * 8;
    const float  bias_v = bias[(size_t)a * DD + ncol];

    __shared__ int s_perm[64];

    for (int m0 = 0; m0 < cnt; m0 += 64) {
        __syncthreads();                              // protect s_perm reuse
        if (tid < 64) {
            int m = m0 + tid;
            s_perm[tid] = (m < cnt) ? perm[base + m] : perm[base];
        }
        __syncthreads();

        const int rem    = cnt - m0;
        const int nchunk = (rem >= 64) ? 4 : ((rem + 15) >> 4);

        // A-frag row pointers: row = l16 within each 16-row chunk.
        const float* xptr[4];
#pragma unroll
        for (int mc = 0; mc < 4; ++mc) {
            int s = s_perm[mc * 16 + l16];
            xptr[mc] = x + (size_t)s * DD + kgrp * 8;
        }

        floatx4 acc[4] = {{0,0,0,0},{0,0,0,0},{0,0,0,0},{0,0,0,0}};

#pragma unroll 2
        for (int ks = 0; ks < DD / 32; ++ks) {
            const float* wp = wrow + ks * 32;
            floatx4 w0 = *(const floatx4*)(wp);
            floatx4 w1 = *(const floatx4*)(wp + 4);
            bf16x8 bfrag = cvt8(w0, w1);
#pragma unroll
            for (int mc = 0; mc < 4; ++mc) {
                if (mc < nchunk) {
                    const float* xp = xptr[mc] + ks * 32;
                    floatx4 x0 = *(const floatx4*)(xp);
                    floatx4 x1 = *(const floatx4*)(xp + 4);
                    bf16x8 afrag = cvt8(x0, x1);
                    acc[mc] = __builtin_amdgcn_mfma_f32_16x16x32_bf16(
                                  afrag, bfrag, acc[mc], 0, 0, 0);
                }
            }
        }

        // C/D layout (verified m89/m91): col = lane&15, row = (lane>>4)*4 + r
        const int rbase = kgrp * 4;
#pragma unroll
        for (int mc = 0; mc < 4; ++mc) {
            if (mc < nchunk) {
#pragma unroll
                for (int r = 0; r < 4; ++r) {
                    int mloc = mc * 16 + rbase + r;
                    if (m0 + mloc < cnt) {
                        int s = s_perm[mloc];
                        out[(size_t)s * DD + ncol] = acc[mc][r] + bias_v;
                    }
                }
            }
        }
    }
}

extern "C" void kernel_launch(void* const* d_in, const int* in_sizes, int n_in,
                              void* d_out, int out_size, void* d_ws, size_t ws_size,
                              hipStream_t stream) {
    const float* x      = (const float*)d_in[0];
    const int*   act    = (const int*)  d_in[1];
    const float* weight = (const float*)d_in[2];
    const float* bias   = (const float*)d_in[3];
    float*       out    = (float*)d_out;

    int* counts  = (int*)d_ws;          // [64]
    int* offsets = counts + NA;         // [64]
    int* perm    = offsets + NA;        // [2048]

    dl_bucket<<<1, 256, 0, stream>>>(act, counts, offsets, perm);
    dl_gemm<<<dim3(8, 64), 256, 0, stream>>>(x, weight, bias,
                                             counts, offsets, perm, out);
}

// Round 2
// 39.116 us; speedup vs baseline: 1.0457x; 1.0457x over previous
//
#include <hip/hip_runtime.h>

// DiscreteLinear: z[b,i] = sum_j weight[a[b],i,j] * x[b,j] + bias[a[b],i]
// B=2048, A=64, D=512.
// R1: latency-bound fix — K-split x4 (each wave owns K=128 of a 16-col tile),
// grid 32x64=2048 blocks -> 8192 waves (4x R0), LDS reduce across k-waves.

#define NA 64
#define DD 512
#define NB 2048
#define KSPLIT 4          // waves per block; each wave covers K = DD/KSPLIT = 128

typedef __bf16  bf16x8  __attribute__((ext_vector_type(8)));
typedef float   floatx4 __attribute__((ext_vector_type(4)));

static __device__ inline bf16x8 cvt8(floatx4 lo, floatx4 hi) {
    bf16x8 r;
    r[0] = (__bf16)lo[0]; r[1] = (__bf16)lo[1];
    r[2] = (__bf16)lo[2]; r[3] = (__bf16)lo[3];
    r[4] = (__bf16)hi[0]; r[5] = (__bf16)hi[1];
    r[6] = (__bf16)hi[2]; r[7] = (__bf16)hi[3];
    return r;
}

// Single block: histogram actions, exclusive scan, scatter sample indices.
__global__ void dl_bucket(const int* __restrict__ act,
                          int* __restrict__ counts,
                          int* __restrict__ offsets,
                          int* __restrict__ perm) {
    __shared__ int s_cnt[NA];
    __shared__ int s_off[NA];
    const int t = threadIdx.x;
    if (t < NA) s_cnt[t] = 0;
    __syncthreads();
    for (int b = t; b < NB; b += 256) atomicAdd(&s_cnt[act[b]], 1);
    __syncthreads();
    if (t == 0) {
        int run = 0;
        for (int i = 0; i < NA; ++i) { s_off[i] = run; run += s_cnt[i]; }
    }
    __syncthreads();
    if (t < NA) { counts[t] = s_cnt[t]; offsets[t] = s_off[t]; }
    __syncthreads();
    for (int b = t; b < NB; b += 256) {
        int pos = atomicAdd(&s_off[act[b]], 1);   // s_off now acts as cursor
        perm[pos] = b;
    }
}

// Grouped GEMM, K-split across the 4 waves of each block.
// grid = (DD/16 = 32 col-tiles, NA actions), block = 256 threads.
// Wave w handles k in [w*128, (w+1)*128) for a 16-column tile; partial
// accumulators reduced through LDS. Each W element is loaded exactly once.
__global__ __launch_bounds__(256, 4) void dl_gemm(
        const float* __restrict__ x,
        const float* __restrict__ weight,
        const float* __restrict__ bias,
        const int*   __restrict__ counts,
        const int*   __restrict__ offsets,
        const int*   __restrict__ perm,
        float*       __restrict__ out)
{
    const int a   = blockIdx.y;
    const int cnt = counts[a];
    if (cnt == 0) return;
    const int base = offsets[a];

    const int tid  = threadIdx.x;
    const int wave = tid >> 6;                 // k-split index 0..3
    const int lane = tid & 63;
    const int l16  = lane & 15;
    const int kgrp = lane >> 4;                // 0..3 within the K=32 MFMA slice
    const int colbase = blockIdx.x * 16;
    const int ncol    = colbase + l16;

    const int koff = wave * (DD / KSPLIT) + kgrp * 8;  // this lane's k start
    const float* wrow = weight + ((size_t)a * DD + ncol) * DD + koff;

    __shared__ int   s_perm[64];
    __shared__ float red[KSPLIT][64][16];      // 16 KB partial accumulators

    for (int m0 = 0; m0 < cnt; m0 += 64) {
        __syncthreads();                       // protect s_perm / red reuse
        if (tid < 64) {
            int m = m0 + tid;
            s_perm[tid] = (m < cnt) ? perm[base + m] : perm[base];
        }
        __syncthreads();

        const int rem    = cnt - m0;
        const int nchunk = (rem >= 64) ? 4 : ((rem + 15) >> 4);

        // A-frag row pointers: row = l16 within each 16-row chunk.
        const float* xptr[4];
#pragma unroll
        for (int mc = 0; mc < 4; ++mc) {
            int s = s_perm[mc * 16 + l16];
            xptr[mc] = x + (size_t)s * DD + koff;
        }

        floatx4 acc[4] = {{0,0,0,0},{0,0,0,0},{0,0,0,0},{0,0,0,0}};

        // 4 K=32 steps per wave (total K=128 per wave).
#pragma unroll 2
        for (int ks = 0; ks < DD / KSPLIT / 32; ++ks) {
            const float* wp = wrow + ks * 32;
            floatx4 w0 = *(const floatx4*)(wp);
            floatx4 w1 = *(const floatx4*)(wp + 4);
            bf16x8 bfrag = cvt8(w0, w1);
#pragma unroll
            for (int mc = 0; mc < 4; ++mc) {
                if (mc < nchunk) {
                    const float* xp = xptr[mc] + ks * 32;
                    floatx4 x0 = *(const floatx4*)(xp);
                    floatx4 x1 = *(const floatx4*)(xp + 4);
                    bf16x8 afrag = cvt8(x0, x1);
                    acc[mc] = __builtin_amdgcn_mfma_f32_16x16x32_bf16(
                                  afrag, bfrag, acc[mc], 0, 0, 0);
                }
            }
        }

        // Write partials: C/D layout row = kgrp*4 + r (within 16-row chunk),
        // col = l16.
#pragma unroll
        for (int mc = 0; mc < 4; ++mc) {
#pragma unroll
            for (int r = 0; r < 4; ++r) {
                red[wave][mc * 16 + kgrp * 4 + r][l16] = acc[mc][r];
            }
        }
        __syncthreads();

        // Reduce 4 k-partials, add bias, scatter to out.
        for (int o = tid; o < 64 * 16; o += 256) {
            int row = o >> 4;
            int col = o & 15;
            if (row < rem) {
                float v = red[0][row][col] + red[1][row][col]
                        + red[2][row][col] + red[3][row][col];
                int s = s_perm[row];
                out[(size_t)s * DD + colbase + col] =
                    v + bias[(size_t)a * DD + colbase + col];
            }
        }
    }
}

extern "C" void kernel_launch(void* const* d_in, const int* in_sizes, int n_in,
                              void* d_out, int out_size, void* d_ws, size_t ws_size,
                              hipStream_t stream) {
    const float* x      = (const float*)d_in[0];
    const int*   act    = (const int*)  d_in[1];
    const float* weight = (const float*)d_in[2];
    const float* bias   = (const float*)d_in[3];
    float*       out    = (float*)d_out;

    int* counts  = (int*)d_ws;          // [64]
    int* offsets = counts + NA;         // [64]
    int* perm    = offsets + NA;        // [2048]

    dl_bucket<<<1, 256, 0, stream>>>(act, counts, offsets, perm);
    dl_gemm<<<dim3(DD / 16, NA), 256, 0, stream>>>(x, weight, bias,
                                                   counts, offsets, perm, out);
}

// Round 3
// 27.116 us; speedup vs baseline: 1.5084x; 1.4425x over previous
//
#include <hip/hip_runtime.h>

// DiscreteLinear: z[b,i] = sum_j weight[a[b],i,j] * x[b,j] + bias[a[b],i]
// B=2048, A=64, D=512.
// R2: kill address divergence. R0/R1 loaded MFMA fragments directly from
// global with lane->row stride 2KB (16-32 transactions per load instr,
// TA-bound). Now: coalesced global float4 loads -> fp32->bf16 cvt in regs ->
// XOR-swizzled LDS -> ds_read_b128 fragments. Double-buffered (T14 split:
// issue loads early, write LDS late).

#define NA 64
#define DD 512
#define NB 2048
#define BN 64           // output cols per block
#define BK 128          // K chunk
#define NKC (DD / BK)   // 4 chunks

typedef __bf16  bf16x8  __attribute__((ext_vector_type(8)));
typedef __bf16  bf16x4  __attribute__((ext_vector_type(4)));
typedef float   floatx4 __attribute__((ext_vector_type(4)));

// Bucket samples by action: histogram + shfl-scan + scatter. One block.
__global__ __launch_bounds__(1024) void dl_bucket(const int* __restrict__ act,
                                                  int* __restrict__ counts,
                                                  int* __restrict__ offsets,
                                                  int* __restrict__ perm) {
    __shared__ int s_cnt[NA];
    __shared__ int s_cur[NA];
    const int t = threadIdx.x;
    if (t < NA) s_cnt[t] = 0;
    __syncthreads();
    for (int b = t; b < NB; b += 1024) atomicAdd(&s_cnt[act[b]], 1);
    __syncthreads();
    if (t < 64) {                       // lanes 0..63 of wave 0
        int v = s_cnt[t];
        int incl = v;
#pragma unroll
        for (int d = 1; d < 64; d <<= 1) {
            int up = __shfl_up(incl, d, 64);
            if (t >= d) incl += up;
        }
        counts[t]  = v;
        offsets[t] = incl - v;
        s_cur[t]   = incl - v;
    }
    __syncthreads();
    for (int b = t; b < NB; b += 1024) {
        int pos = atomicAdd(&s_cur[act[b]], 1);
        perm[pos] = b;
    }
}

// Grouped GEMM. grid = (64 actions, 8 col-tiles), block = 256 (4 waves).
// Wave w owns cols [colbase + 16w, +16). Per K-chunk: coalesced stage of
// W[64 x 128] and x[rem x 128] into swizzled bf16 LDS, then MFMA.
__global__ __launch_bounds__(256, 2) void dl_gemm(
        const float* __restrict__ x,
        const float* __restrict__ weight,
        const float* __restrict__ bias,
        const int*   __restrict__ counts,
        const int*   __restrict__ offsets,
        const int*   __restrict__ perm,
        float*       __restrict__ out)
{
    const int a   = blockIdx.x;          // action-major: 8 tiles of one action
    const int cnt = counts[a];           // land on the same XCD (ids differ by 64)
    if (cnt == 0) return;
    const int base = offsets[a];

    const int tid  = threadIdx.x;
    const int wave = tid >> 6;
    const int lane = tid & 63;
    const int l16  = lane & 15;
    const int kgrp = lane >> 4;
    const int colbase = blockIdx.y * BN;
    const int ncol    = colbase + wave * 16 + l16;

    // staging coords: 32 lanes per row, float4 each -> 512B contiguous/row
    const int srow = tid >> 5;           // 0..7, +8 per step
    const int skk  = (tid & 31) << 2;    // float index 0..124

    const float* wtile  = weight + ((size_t)a * DD + colbase) * DD;
    const float  bias_v = bias[(size_t)a * DD + ncol];

    __shared__ __align__(16) __bf16 Ws[2][BN][BK];   // 32 KB
    __shared__ __align__(16) __bf16 Xs[2][BN][BK];   // 32 KB
    __shared__ int s_perm[64];

    const int swzl = (l16 & 7) << 3;     // read swizzle (bf16 idx ^= (row&7)<<3)

    for (int m0 = 0; m0 < cnt; m0 += 64) {
        __syncthreads();
        if (tid < 64) {
            int m = m0 + tid;
            s_perm[tid] = (m < cnt) ? perm[base + m] : perm[base];
        }
        __syncthreads();
        const int rem    = min(cnt - m0, 64);
        const int nchunk = (rem + 15) >> 4;

        floatx4 wreg[8], xreg[8];
        // prologue: load chunk 0, write buf 0
#pragma unroll
        for (int i = 0; i < 8; ++i) {
            const int r  = srow + i * 8;
            const int xr = (r < rem) ? r : (rem - 1);
            wreg[i] = *(const floatx4*)(wtile + (size_t)r * DD + skk);
            xreg[i] = *(const floatx4*)(x + (size_t)s_perm[xr] * DD + skk);
        }
#pragma unroll
        for (int i = 0; i < 8; ++i) {
            const int r  = srow + i * 8;
            const int cc = skk ^ ((r & 7) << 3);
            bf16x4 wv, xv;
#pragma unroll
            for (int j = 0; j < 4; ++j) {
                wv[j] = (__bf16)wreg[i][j];
                xv[j] = (__bf16)xreg[i][j];
            }
            *(bf16x4*)&Ws[0][r][cc] = wv;
            *(bf16x4*)&Xs[0][r][cc] = xv;
        }

        floatx4 acc[4] = {{0,0,0,0},{0,0,0,0},{0,0,0,0},{0,0,0,0}};

        for (int kc = 0; kc < NKC; ++kc) {
            const int cur = kc & 1;
            // T14: issue next chunk's global loads BEFORE computing this one
            if (kc + 1 < NKC) {
                const int ko = (kc + 1) * BK;
#pragma unroll
                for (int i = 0; i < 8; ++i) {
                    const int r  = srow + i * 8;
                    const int xr = (r < rem) ? r : (rem - 1);
                    wreg[i] = *(const floatx4*)(wtile + (size_t)r * DD + ko + skk);
                    xreg[i] = *(const floatx4*)(x + (size_t)s_perm[xr] * DD + ko + skk);
                }
            }
            __syncthreads();             // buf[cur] writes visible
#pragma unroll
            for (int ks = 0; ks < BK / 32; ++ks) {
                const int kb = (ks * 32 + kgrp * 8) ^ swzl;
                const bf16x8 bfrag = *(const bf16x8*)&Ws[cur][wave * 16 + l16][kb];
#pragma unroll
                for (int mc = 0; mc < 4; ++mc) {
                    if (mc < nchunk) {
                        const bf16x8 afrag = *(const bf16x8*)&Xs[cur][mc * 16 + l16][kb];
                        acc[mc] = __builtin_amdgcn_mfma_f32_16x16x32_bf16(
                                      afrag, bfrag, acc[mc], 0, 0, 0);
                    }
                }
            }
            __syncthreads();             // everyone done reading buf[cur^1] long ago;
            if (kc + 1 < NKC) {          // safe to overwrite buf[cur^1]
#pragma unroll
                for (int i = 0; i < 8; ++i) {
                    const int r  = srow + i * 8;
                    const int cc = skk ^ ((r & 7) << 3);
                    bf16x4 wv, xv;
#pragma unroll
                    for (int j = 0; j < 4; ++j) {
                        wv[j] = (__bf16)wreg[i][j];
                        xv[j] = (__bf16)xreg[i][j];
                    }
                    *(bf16x4*)&Ws[cur ^ 1][r][cc] = wv;
                    *(bf16x4*)&Xs[cur ^ 1][r][cc] = xv;
                }
            }
        }

        // Epilogue: C/D layout col = lane&15 (-> ncol), row = kgrp*4 + r.
#pragma unroll
        for (int mc = 0; mc < 4; ++mc) {
            if (mc < nchunk) {
#pragma unroll
                for (int r = 0; r < 4; ++r) {
                    const int mloc = mc * 16 + kgrp * 4 + r;
                    if (mloc < rem) {
                        out[(size_t)s_perm[mloc] * DD + ncol] = acc[mc][r] + bias_v;
                    }
                }
            }
        }
    }
}

extern "C" void kernel_launch(void* const* d_in, const int* in_sizes, int n_in,
                              void* d_out, int out_size, void* d_ws, size_t ws_size,
                              hipStream_t stream) {
    const float* x      = (const float*)d_in[0];
    const int*   act    = (const int*)  d_in[1];
    const float* weight = (const float*)d_in[2];
    const float* bias   = (const float*)d_in[3];
    float*       out    = (float*)d_out;

    int* counts  = (int*)d_ws;          // [64]
    int* offsets = counts + NA;         // [64]
    int* perm    = offsets + NA;        // [2048]

    dl_bucket<<<1, 1024, 0, stream>>>(act, counts, offsets, perm);
    dl_gemm<<<dim3(NA, DD / BN), 256, 0, stream>>>(x, weight, bias,
                                                   counts, offsets, perm, out);
}